// Round 1
// baseline (368.584 us; speedup 1.0000x reference)
//
#include <hip/hip_runtime.h>

// ScRRAMBLe layer: x[512*4*64] -> route(Ci) -> per-core 256x256 matvec (Wi) ->
// capped-relu -> route(C_cores) -> per-core matvec (Wo) -> capped-relu.
// Memory-bound: must stream Wi+Wo (2 x 128 MiB fp32) + Ci/C_cores (2 x 16 MiB).

#define N_CORES 512
#define SLOTS 4
#define SLOT_LEN 64
#define CORE_VEC 256            // SLOTS*SLOT_LEN
#define H_ELEMS (N_CORES * CORE_VEC)   // 131072 floats per intermediate buffer

__device__ __forceinline__ float capped_relu(float v) {
    return fminf(fmaxf(v, 0.0f), 10.0f);
}

// Dense scan of routing tensor C [I,J,K,L] (=[512,4,512,4]); for each nonzero
// count c at (ij, kl): h[kl, 0:64] += c * src[ij, 0:64].
// One thread per 4 consecutive entries (one (i,j,k) row of l), coalesced float4 read.
__global__ __launch_bounds__(256) void scatter_route(const float* __restrict__ C,
                                                     const float* __restrict__ src,
                                                     float* __restrict__ h) {
    int t = blockIdx.x * blockDim.x + threadIdx.x;   // 0 .. 1048575
    const float4 c4 = reinterpret_cast<const float4*>(C)[t];
    int base = t << 2;               // flat index into C
    int ij  = base >> 11;            // i*4 + j   (source slot)
    int kl0 = base & 2047;           // k*4 + l   (dest slot), l = 0 here
    float cs[4] = {c4.x, c4.y, c4.z, c4.w};
    #pragma unroll
    for (int q = 0; q < 4; ++q) {
        float c = cs[q];
        if (c != 0.0f) {
            const float* xp = src + ij * SLOT_LEN;
            float* hp = h + (kl0 + q) * SLOT_LEN;
            for (int m = 0; m < SLOT_LEN; ++m) {
                atomicAdd(hp + m, c * xp[m]);
            }
        }
    }
}

// Per-core matvec: out[i, j, l] = act( sum_{k,m} W[i,j,k,l,m] * h[i, k, m] ).
// W layout: [512, 4, 4, 64, 64] (m contiguous, then l, then k, then j, then i).
// Block = 256 threads = 4 waves, one block per (i,j). Wave w handles row-groups
// r = w*4 .. w*4+3 (rows r*4+g). Lane t: g = t>>4 selects row within group,
// c16 = t&15 selects 4 contiguous columns m = c16*4..+3 -> the wave's
// global_load_dwordx4 covers a contiguous 1 KiB chunk (perfect coalescing).
// Partial dot is reduced across the 16 lanes of a column-group via shfl_xor.
__global__ __launch_bounds__(256) void core_gemv(const float* __restrict__ W,
                                                 const float* __restrict__ h,
                                                 float* __restrict__ out) {
    const int i = blockIdx.x >> 2;
    const int j = blockIdx.x & 3;
    const int t = threadIdx.x & 63;
    const int w = threadIdx.x >> 6;
    const int g = t >> 4;        // row within group of 4
    const int c16 = t & 15;      // column chunk (4 floats)

    // h values this lane needs: h[i, k, c16*4 + 0..3] for k = 0..3 (constant per lane)
    float4 hk[SLOTS];
    #pragma unroll
    for (int k = 0; k < SLOTS; ++k) {
        hk[k] = *reinterpret_cast<const float4*>(h + i * CORE_VEC + k * SLOT_LEN + c16 * 4);
    }

    // Weight base for (i, j): 4 k-tiles of 64*64 floats each
    const float* Wb = W + (size_t)(i * SLOTS + j) * (SLOTS * SLOT_LEN * SLOT_LEN);

    #pragma unroll
    for (int rr = 0; rr < 4; ++rr) {
        const int r = w * 4 + rr;          // 0..15; rows r*4 .. r*4+3
        float p = 0.0f;
        #pragma unroll
        for (int k = 0; k < SLOTS; ++k) {
            // lane reads W[i,j,k, r*4+g, c16*4 .. +3] — wave-contiguous 1 KiB
            float4 a = *reinterpret_cast<const float4*>(Wb + k * (SLOT_LEN * SLOT_LEN)
                                                        + r * 256 + t * 4);
            p += a.x * hk[k].x + a.y * hk[k].y + a.z * hk[k].z + a.w * hk[k].w;
        }
        // reduce across the 16 lanes sharing a row (xor 1,2,4,8 stays within group)
        p += __shfl_xor(p, 1);
        p += __shfl_xor(p, 2);
        p += __shfl_xor(p, 4);
        p += __shfl_xor(p, 8);
        if (c16 == 0) {
            out[(i * SLOTS + j) * SLOT_LEN + r * 4 + g] = capped_relu(p);
        }
    }
}

extern "C" void kernel_launch(void* const* d_in, const int* in_sizes, int n_in,
                              void* d_out, int out_size, void* d_ws, size_t ws_size,
                              hipStream_t stream) {
    const float* x  = (const float*)d_in[0];   // [131072]
    const float* Wi = (const float*)d_in[1];   // [512,4,4,64,64]
    const float* Wo = (const float*)d_in[2];   // [512,4,4,64,64]
    const float* Ci = (const float*)d_in[3];   // [512,4,512,4]
    const float* Cc = (const float*)d_in[4];   // [512,4,512,4]
    float* out = (float*)d_out;                // [512,4,64]

    float* h1 = (float*)d_ws;            // [131072]
    float* h2 = h1 + H_ELEMS;            // [131072]
    float* y1 = h1 + 2 * H_ELEMS;        // [131072]

    // zero the two routing accumulators (h1, h2 are adjacent)
    hipMemsetAsync(d_ws, 0, 2 * H_ELEMS * sizeof(float), stream);

    // layer 1: route x -> h1, per-core matvec Wi -> y1 (with activation)
    scatter_route<<<4096, 256, 0, stream>>>(Ci, x, h1);
    core_gemv<<<2048, 256, 0, stream>>>(Wi, h1, y1);

    // layer 2: route y1 -> h2, per-core matvec Wo -> out (with activation)
    scatter_route<<<4096, 256, 0, stream>>>(Cc, y1, h2);
    core_gemv<<<2048, 256, 0, stream>>>(Wo, h2, out);
}

// Round 2
// 311.842 us; speedup vs baseline: 1.1820x; 1.1820x over previous
//
#include <hip/hip_runtime.h>

// ScRRAMBLe layer: x[512*4*64] -> route(Ci) -> per-core 256x256 matvec (Wi) ->
// capped-relu -> route(C_cores) -> per-core matvec (Wo) -> capped-relu.
// Memory-bound floor: Wi+Wo (2 x 128 MiB) + Ci/C_cores (2 x 16 MiB) ~= 48 us.
//
// R2: routing rewritten wave-cooperative (one 64-lane coalesced atomicAdd per
// nonzero entry instead of a serial 64-iter scalar-atomic loop under a sparse
// exec mask); gemv1 fused with route2 (y1 staged in LDS, scattered directly).

#define N_CORES 512
#define SLOTS 4
#define SLOT_LEN 64
#define CORE_VEC 256                     // SLOTS*SLOT_LEN
#define H_ELEMS (N_CORES * CORE_VEC)     // 131072 floats per h buffer
#define ROW_LEN 2048                     // K*L = 512*4 entries per source row

__device__ __forceinline__ float capped_relu(float v) {
    return fminf(fmaxf(v, 0.0f), 10.0f);
}

// Scan one source row C[ij, 0:2048] with one wave; for each nonzero count c at
// dst kl: h[kl, lane] += c * src[ij, lane]  (one coalesced 64-lane atomic).
__device__ __forceinline__ void route_row_wave(const float* __restrict__ row,
                                               float srcval, int lane,
                                               float* __restrict__ h,
                                               int chunk_begin, int chunk_end) {
    for (int chunk = chunk_begin; chunk < chunk_end; ++chunk) {
        float4 c4 = reinterpret_cast<const float4*>(row)[chunk * 64 + lane];
        float cs[4] = {c4.x, c4.y, c4.z, c4.w};
        #pragma unroll
        for (int q = 0; q < 4; ++q) {
            unsigned long long m = __ballot(cs[q] != 0.0f);
            while (m) {
                int L = __ffsll(m) - 1;
                m &= m - 1;
                float c = __shfl(cs[q], L, 64);
                int dst = chunk * 256 + L * 4 + q;     // kl index
                atomicAdd(h + dst * SLOT_LEN + lane, c * srcval);
            }
        }
    }
}

// Layer-1 routing: one wave per source slot ij (2048 waves).
__global__ __launch_bounds__(256) void route_src(const float* __restrict__ C,
                                                 const float* __restrict__ src,
                                                 float* __restrict__ h) {
    const int wave = blockIdx.x * 4 + (threadIdx.x >> 6);   // ij in 0..2047
    const int lane = threadIdx.x & 63;
    const float xv = src[wave * SLOT_LEN + lane];
    const float* row = C + (size_t)wave * ROW_LEN;
    route_row_wave(row, xv, lane, h, 0, 8);
}

// Fused: per-core matvec y1[i,j,:] = act(Wi[i,j]·h1[i]) staged in LDS, then the
// block scatters y1 through C2 row (i,j) into h2 (each wave takes 2 chunks).
// W layout [512,4,4,64,64]: wave-contiguous 1 KiB loads (lane t -> row r*4+(t>>4),
// cols (t&15)*4..+3), 16-lane shfl_xor reduction.
__global__ __launch_bounds__(256) void gemv_route(const float* __restrict__ W,
                                                  const float* __restrict__ h,
                                                  const float* __restrict__ C2,
                                                  float* __restrict__ h2) {
    __shared__ float ly[SLOT_LEN];
    const int i = blockIdx.x >> 2;
    const int j = blockIdx.x & 3;
    const int t = threadIdx.x & 63;
    const int w = threadIdx.x >> 6;
    const int g = t >> 4;
    const int c16 = t & 15;

    float4 hk[SLOTS];
    #pragma unroll
    for (int k = 0; k < SLOTS; ++k)
        hk[k] = *reinterpret_cast<const float4*>(h + i * CORE_VEC + k * SLOT_LEN + c16 * 4);

    const float* Wb = W + (size_t)(i * SLOTS + j) * (SLOTS * SLOT_LEN * SLOT_LEN);

    #pragma unroll
    for (int rr = 0; rr < 4; ++rr) {
        const int r = w * 4 + rr;          // 0..15
        float p = 0.0f;
        #pragma unroll
        for (int k = 0; k < SLOTS; ++k) {
            float4 a = *reinterpret_cast<const float4*>(Wb + k * (SLOT_LEN * SLOT_LEN)
                                                        + r * 256 + t * 4);
            p += a.x * hk[k].x + a.y * hk[k].y + a.z * hk[k].z + a.w * hk[k].w;
        }
        p += __shfl_xor(p, 1);
        p += __shfl_xor(p, 2);
        p += __shfl_xor(p, 4);
        p += __shfl_xor(p, 8);
        if (c16 == 0) ly[r * 4 + g] = capped_relu(p);
    }
    __syncthreads();

    const float yv = ly[t];
    const float* row = C2 + (size_t)(i * SLOTS + j) * ROW_LEN;
    route_row_wave(row, yv, t, h2, w * 2, w * 2 + 2);   // wave w: chunks 2w,2w+1
}

// Final per-core matvec: out[i,j,:] = act(Wo[i,j]·h2[i]).
__global__ __launch_bounds__(256) void core_gemv(const float* __restrict__ W,
                                                 const float* __restrict__ h,
                                                 float* __restrict__ out) {
    const int i = blockIdx.x >> 2;
    const int j = blockIdx.x & 3;
    const int t = threadIdx.x & 63;
    const int w = threadIdx.x >> 6;
    const int g = t >> 4;
    const int c16 = t & 15;

    float4 hk[SLOTS];
    #pragma unroll
    for (int k = 0; k < SLOTS; ++k)
        hk[k] = *reinterpret_cast<const float4*>(h + i * CORE_VEC + k * SLOT_LEN + c16 * 4);

    const float* Wb = W + (size_t)(i * SLOTS + j) * (SLOTS * SLOT_LEN * SLOT_LEN);

    #pragma unroll
    for (int rr = 0; rr < 4; ++rr) {
        const int r = w * 4 + rr;
        float p = 0.0f;
        #pragma unroll
        for (int k = 0; k < SLOTS; ++k) {
            float4 a = *reinterpret_cast<const float4*>(Wb + k * (SLOT_LEN * SLOT_LEN)
                                                        + r * 256 + t * 4);
            p += a.x * hk[k].x + a.y * hk[k].y + a.z * hk[k].z + a.w * hk[k].w;
        }
        p += __shfl_xor(p, 1);
        p += __shfl_xor(p, 2);
        p += __shfl_xor(p, 4);
        p += __shfl_xor(p, 8);
        if (c16 == 0)
            out[(i * SLOTS + j) * SLOT_LEN + r * 4 + g] = capped_relu(p);
    }
}

extern "C" void kernel_launch(void* const* d_in, const int* in_sizes, int n_in,
                              void* d_out, int out_size, void* d_ws, size_t ws_size,
                              hipStream_t stream) {
    const float* x  = (const float*)d_in[0];   // [131072]
    const float* Wi = (const float*)d_in[1];   // [512,4,4,64,64]
    const float* Wo = (const float*)d_in[2];   // [512,4,4,64,64]
    const float* Ci = (const float*)d_in[3];   // [512,4,512,4]
    const float* Cc = (const float*)d_in[4];   // [512,4,512,4]
    float* out = (float*)d_out;                // [512,4,64]

    float* h1 = (float*)d_ws;            // [131072]
    float* h2 = h1 + H_ELEMS;            // [131072]

    // zero the two routing accumulators (adjacent)
    hipMemsetAsync(d_ws, 0, 2 * H_ELEMS * sizeof(float), stream);

    // layer 1 routing: x -> h1 (wave-cooperative scatter)
    route_src<<<512, 256, 0, stream>>>(Ci, x, h1);
    // fused: y1 = act(Wi·h1) staged in LDS, scattered through Cc -> h2
    gemv_route<<<2048, 256, 0, stream>>>(Wi, h1, Cc, h2);
    // final matvec: out = act(Wo·h2)
    core_gemv<<<2048, 256, 0, stream>>>(Wo, h2, out);
}

// Round 3
// 291.203 us; speedup vs baseline: 1.2657x; 1.0709x over previous
//
#include <hip/hip_runtime.h>

// ScRRAMBLe layer: x[512*4*64] -> route(Ci) -> per-core 256x256 matvec (Wi) ->
// capped-relu -> route(C_cores) -> per-core matvec (Wo) -> capped-relu.
// Memory-bound floor: Wi+Wo (2 x 128 MiB) + Ci/C_cores (2 x 16 MiB) ~= 44 us
// at the measured 7.0 TB/s achievable BW.
//
// R3: (1) Cc row prefetched into registers before the W stream in gemv_route
// (routing-scatter latency overlapped with weight streaming); (2) h2 zeroed as
// side work inside route_src (memset now covers h1 only); (3) nontemporal
// loads on the weight stream (no reuse -> don't evict h/Cc from L2).

#define N_CORES 512
#define SLOTS 4
#define SLOT_LEN 64
#define CORE_VEC 256                     // SLOTS*SLOT_LEN
#define H_ELEMS (N_CORES * CORE_VEC)     // 131072 floats per h buffer
#define ROW_LEN 2048                     // K*L = 512*4 entries per source row

typedef float v4f __attribute__((ext_vector_type(4)));

__device__ __forceinline__ float capped_relu(float v) {
    return fminf(fmaxf(v, 0.0f), 10.0f);
}

// Layer-1 routing: one wave per source slot ij (2048 waves). Wave scans its
// contiguous 8 KiB row of Ci; for each nonzero count c at dst kl, issues one
// coalesced 64-lane atomicAdd: h1[kl, lane] += c * x[ij, lane].
// Side work: thread gid zeroes h2[gid] (grid exactly covers H_ELEMS; ordered
// before gemv_route's atomics by the kernel boundary).
__global__ __launch_bounds__(256) void route_src(const float* __restrict__ C,
                                                 const float* __restrict__ src,
                                                 float* __restrict__ h1,
                                                 float* __restrict__ h2) {
    const int gid = blockIdx.x * 256 + threadIdx.x;
    h2[gid] = 0.0f;

    const int wave = blockIdx.x * 4 + (threadIdx.x >> 6);   // ij in 0..2047
    const int lane = threadIdx.x & 63;
    const float xv = src[wave * SLOT_LEN + lane];
    const float* row = C + (size_t)wave * ROW_LEN;

    for (int chunk = 0; chunk < 8; ++chunk) {
        v4f c4 = __builtin_nontemporal_load(
            reinterpret_cast<const v4f*>(row) + chunk * 64 + lane);
        #pragma unroll
        for (int q = 0; q < 4; ++q) {
            float cq = c4[q];
            unsigned long long m = __ballot(cq != 0.0f);
            while (m) {
                int L = __ffsll(m) - 1;
                m &= m - 1;
                float c = __shfl(cq, L, 64);
                int dst = chunk * 256 + L * 4 + q;     // kl index
                atomicAdd(h1 + dst * SLOT_LEN + lane, c * xv);
            }
        }
    }
}

// Fused: per-core matvec y1[i,j,:] = act(Wi[i,j]·h1[i]) staged in LDS, then the
// block scatters y1 through Cc row (i,j) into h2. Cc row is prefetched into
// registers (2 x float4 per lane) BEFORE the weight stream so its latency is
// hidden. W layout [512,4,4,64,64]: wave-contiguous 1 KiB loads (lane t ->
// row r*4+(t>>4), cols (t&15)*4..+3), 16-lane shfl_xor reduction.
__global__ __launch_bounds__(256) void gemv_route(const float* __restrict__ W,
                                                  const float* __restrict__ h,
                                                  const float* __restrict__ C2,
                                                  float* __restrict__ h2) {
    __shared__ float ly[SLOT_LEN];
    const int i = blockIdx.x >> 2;
    const int j = blockIdx.x & 3;
    const int t = threadIdx.x & 63;
    const int w = threadIdx.x >> 6;
    const int g = t >> 4;
    const int c16 = t & 15;

    // prefetch this wave's 2 chunks of the Cc routing row (overlaps W stream)
    const float* row = C2 + (size_t)(i * SLOTS + j) * ROW_LEN;
    v4f cpre[2];
    #pragma unroll
    for (int cc = 0; cc < 2; ++cc)
        cpre[cc] = __builtin_nontemporal_load(
            reinterpret_cast<const v4f*>(row) + (w * 2 + cc) * 64 + t);

    v4f hk[SLOTS];
    #pragma unroll
    for (int k = 0; k < SLOTS; ++k)
        hk[k] = *reinterpret_cast<const v4f*>(h + i * CORE_VEC + k * SLOT_LEN + c16 * 4);

    const float* Wb = W + (size_t)(i * SLOTS + j) * (SLOTS * SLOT_LEN * SLOT_LEN);

    #pragma unroll
    for (int rr = 0; rr < 4; ++rr) {
        const int r = w * 4 + rr;          // 0..15
        float p = 0.0f;
        #pragma unroll
        for (int k = 0; k < SLOTS; ++k) {
            v4f a = __builtin_nontemporal_load(
                reinterpret_cast<const v4f*>(Wb + k * (SLOT_LEN * SLOT_LEN)
                                             + r * 256 + t * 4));
            p += a.x * hk[k].x + a.y * hk[k].y + a.z * hk[k].z + a.w * hk[k].w;
        }
        p += __shfl_xor(p, 1);
        p += __shfl_xor(p, 2);
        p += __shfl_xor(p, 4);
        p += __shfl_xor(p, 8);
        if (c16 == 0) ly[r * 4 + g] = capped_relu(p);
    }
    __syncthreads();

    const float yv = ly[t];
    #pragma unroll
    for (int cc = 0; cc < 2; ++cc) {
        const int chunk = w * 2 + cc;
        #pragma unroll
        for (int q = 0; q < 4; ++q) {
            float cq = cpre[cc][q];
            unsigned long long m = __ballot(cq != 0.0f);
            while (m) {
                int L = __ffsll(m) - 1;
                m &= m - 1;
                float c = __shfl(cq, L, 64);
                int dst = chunk * 256 + L * 4 + q;
                atomicAdd(h2 + dst * SLOT_LEN + t, c * yv);
            }
        }
    }
}

// Final per-core matvec: out[i,j,:] = act(Wo[i,j]·h2[i]).
__global__ __launch_bounds__(256) void core_gemv(const float* __restrict__ W,
                                                 const float* __restrict__ h,
                                                 float* __restrict__ out) {
    const int i = blockIdx.x >> 2;
    const int j = blockIdx.x & 3;
    const int t = threadIdx.x & 63;
    const int w = threadIdx.x >> 6;
    const int g = t >> 4;
    const int c16 = t & 15;

    v4f hk[SLOTS];
    #pragma unroll
    for (int k = 0; k < SLOTS; ++k)
        hk[k] = *reinterpret_cast<const v4f*>(h + i * CORE_VEC + k * SLOT_LEN + c16 * 4);

    const float* Wb = W + (size_t)(i * SLOTS + j) * (SLOTS * SLOT_LEN * SLOT_LEN);

    #pragma unroll
    for (int rr = 0; rr < 4; ++rr) {
        const int r = w * 4 + rr;
        float p = 0.0f;
        #pragma unroll
        for (int k = 0; k < SLOTS; ++k) {
            v4f a = __builtin_nontemporal_load(
                reinterpret_cast<const v4f*>(Wb + k * (SLOT_LEN * SLOT_LEN)
                                             + r * 256 + t * 4));
            p += a.x * hk[k].x + a.y * hk[k].y + a.z * hk[k].z + a.w * hk[k].w;
        }
        p += __shfl_xor(p, 1);
        p += __shfl_xor(p, 2);
        p += __shfl_xor(p, 4);
        p += __shfl_xor(p, 8);
        if (c16 == 0)
            out[(i * SLOTS + j) * SLOT_LEN + r * 4 + g] = capped_relu(p);
    }
}

extern "C" void kernel_launch(void* const* d_in, const int* in_sizes, int n_in,
                              void* d_out, int out_size, void* d_ws, size_t ws_size,
                              hipStream_t stream) {
    const float* x  = (const float*)d_in[0];   // [131072]
    const float* Wi = (const float*)d_in[1];   // [512,4,4,64,64]
    const float* Wo = (const float*)d_in[2];   // [512,4,4,64,64]
    const float* Ci = (const float*)d_in[3];   // [512,4,512,4]
    const float* Cc = (const float*)d_in[4];   // [512,4,512,4]
    float* out = (float*)d_out;                // [512,4,64]

    float* h1 = (float*)d_ws;            // [131072]
    float* h2 = h1 + H_ELEMS;            // [131072]

    // zero only h1; h2 is zeroed as side work inside route_src
    hipMemsetAsync(h1, 0, H_ELEMS * sizeof(float), stream);

    // layer-1 routing: x -> h1 (wave-cooperative scatter) + zero h2
    route_src<<<512, 256, 0, stream>>>(Ci, x, h1, h2);
    // fused: y1 = act(Wi·h1) staged in LDS, scattered through Cc -> h2
    gemv_route<<<2048, 256, 0, stream>>>(Wi, h1, Cc, h2);
    // final matvec: out = act(Wo·h2)
    core_gemv<<<2048, 256, 0, stream>>>(Wo, h2, out);
}